// Round 19
// baseline (111.392 us; speedup 1.0000x reference)
//
#include <hip/hip_runtime.h>
#include <math.h>

#define BATCH 32
#define CH 256
#define HW 4096
#define KSEL 8
#define EPSV 1e-5f

typedef __attribute__((ext_vector_type(8))) short short8;
typedef __attribute__((ext_vector_type(4))) float f32x4;

// ---- K1: raw-x Gram partials (256x256 per (b,q)) + fused s/sq partials ----
// ISSUE-EARLY region order (the untried placement): per chunk
//   [ LOAD(k+1) -> pin -> MFMA(k) -> CONVERT(k+1) -> lgkm -> barrier ]
// All prior variants issued loads immediately before a barrier (R13 top-issue,
// R16/17 late-issue) -> if the barrier drains vmcnt, HBM latency+transfer is
// fully exposed -> measured 1.9 TB/s serial floor (21.6k cyc/chunk). Here a
// whole MFMA+ds_read phase (~4k cyc) sits between issue and barrier, so vmcnt
// is ~drained naturally by barrier time.
// 1024 thr = 16 waves (4x4), wave tile 64x64, acc[4][4]=64 VGPR, LDS dbuf
// 128 KB, one raw s_barrier per chunk. Data path = R7 proven: coalesced wave
// loads -> reg trunc-split convert -> LDS stride 128B + 3-bit granule XOR
// (0 conflicts) -> bf16 16x16x32 MFMA. C1 = H*(H+2L)^T trunc split.
__global__ __launch_bounds__(1024) void gram256(const float* __restrict__ x,
                                                float* __restrict__ cosP,
                                                float* __restrict__ sP,
                                                float* __restrict__ sqP) {
    int z = blockIdx.x;             // 0..255
    int b = z >> 3, q = z & 7;      // klen = 512
    const float* xb = x + (size_t)b * CH * HW;

    __shared__ unsigned short Hh[2][CH * 64];   // 2 x 32 KB
    __shared__ unsigned short Hl[2][CH * 64];   // 2 x 32 KB

    int t = threadIdx.x, lane = t & 63, w = t >> 6;   // w 0..15
    int wr = (w >> 2) * 64, wc = (w & 3) * 64;
    int fr = lane & 15, fg = lane >> 4;

    // staging geometry (coalesced: 4 x 1KB contiguous per wave-load instr)
    int rowbase = t >> 4;            // 0..63 ; row_i = rowbase + 64*i
    int col16 = t & 15;              // 16B chunk within the 256B row-chunk
    int gr = col16 >> 1;             // granule 0..7
    int halfo = (col16 & 1) * 4;     // short offset within granule
    const float4* srcb4 = (const float4*)xb + (size_t)rowbase * (HW / 4) + q * 128 + col16;

    float sl[4] = {}, sql[4] = {};
    f32x4 acc[4][4] = {};
    float4 f[4];

#define LOAD4(KB) { const float4* sp = srcb4 + (size_t)(KB) * 16;                  \
    _Pragma("unroll") for (int i = 0; i < 4; ++i) f[i] = sp[(size_t)i * 65536]; }

#define CONVERT4(BUF) { _Pragma("unroll") for (int i = 0; i < 4; ++i) {            \
    float4 v = f[i];                                                               \
    sl[i] += v.x + v.y + v.z + v.w;                                                \
    sql[i] += v.x * v.x + v.y * v.y + v.z * v.z + v.w * v.w;                       \
    unsigned u0 = __float_as_uint(v.x), u1 = __float_as_uint(v.y);                 \
    unsigned u2 = __float_as_uint(v.z), u3 = __float_as_uint(v.w);                 \
    unsigned hp0 = (u0 >> 16) | (u1 & 0xffff0000u);                                \
    unsigned hp1 = (u2 >> 16) | (u3 & 0xffff0000u);                                \
    float lo0 = v.x - __uint_as_float(u0 & 0xffff0000u);                           \
    float lo1 = v.y - __uint_as_float(u1 & 0xffff0000u);                           \
    float lo2 = v.z - __uint_as_float(u2 & 0xffff0000u);                           \
    float lo3 = v.w - __uint_as_float(u3 & 0xffff0000u);                           \
    lo0 += lo0; lo1 += lo1; lo2 += lo2; lo3 += lo3;                                \
    unsigned lp0 = (__float_as_uint(lo0) >> 16) | (__float_as_uint(lo1) & 0xffff0000u); \
    unsigned lp1 = (__float_as_uint(lo2) >> 16) | (__float_as_uint(lo3) & 0xffff0000u); \
    int r = rowbase + 64 * i;                                                      \
    int adr = r * 64 + ((gr ^ (r & 7)) * 8) + halfo;                               \
    *(uint2*)&Hh[BUF][adr] = make_uint2(hp0, hp1);                                 \
    *(uint2*)&Hl[BUF][adr] = make_uint2(lp0, lp1);                                 \
} }

// bh-pass then bl-pass: same-acc MFMAs separated by 16 independent instrs.
#define MFMA_PHASE(BUF) { _Pragma("unroll") for (int ks = 0; ks < 2; ++ks) {       \
    int gk = ks * 4 + fg;                                                          \
    short8 af[4], bb[4];                                                           \
    _Pragma("unroll") for (int mi = 0; mi < 4; ++mi) {                             \
        int r = wr + mi * 16 + fr;                                                 \
        af[mi] = *(const short8*)&Hh[BUF][r * 64 + ((gk ^ (r & 7)) * 8)];          \
    }                                                                              \
    _Pragma("unroll") for (int nj = 0; nj < 4; ++nj) {                             \
        int r = wc + nj * 16 + fr;                                                 \
        bb[nj] = *(const short8*)&Hh[BUF][r * 64 + ((gk ^ (r & 7)) * 8)];          \
    }                                                                              \
    _Pragma("unroll") for (int nj = 0; nj < 4; ++nj)                               \
        _Pragma("unroll") for (int mi = 0; mi < 4; ++mi)                           \
            acc[mi][nj] = __builtin_amdgcn_mfma_f32_16x16x32_bf16(af[mi], bb[nj], acc[mi][nj], 0, 0, 0); \
    _Pragma("unroll") for (int nj = 0; nj < 4; ++nj) {                             \
        int r = wc + nj * 16 + fr;                                                 \
        bb[nj] = *(const short8*)&Hl[BUF][r * 64 + ((gk ^ (r & 7)) * 8)];          \
    }                                                                              \
    _Pragma("unroll") for (int nj = 0; nj < 4; ++nj)                               \
        _Pragma("unroll") for (int mi = 0; mi < 4; ++mi)                           \
            acc[mi][nj] = __builtin_amdgcn_mfma_f32_16x16x32_bf16(af[mi], bb[nj], acc[mi][nj], 0, 0, 0); \
} }

    // prologue: stage chunk 0 into buf0
    LOAD4(0)
    CONVERT4(0)
    asm volatile("s_waitcnt lgkmcnt(0)" ::: "memory");
    __builtin_amdgcn_sched_barrier(0);
    __builtin_amdgcn_s_barrier();

#pragma unroll 1
    for (int kb = 0; kb < 8; ++kb) {
        if (kb < 7) {
            LOAD4(kb + 1)                        // issue EARLY...
            asm volatile("" ::: "memory");       // ...and pin: loads cannot sink below
        }
        MFMA_PHASE(kb & 1)                       // ~4k cyc covers HBM latency+transfer
        if (kb < 7) {
            CONVERT4((kb + 1) & 1)               // f ready (counted vmcnt, mostly satisfied)
            asm volatile("s_waitcnt lgkmcnt(0)" ::: "memory");
            __builtin_amdgcn_sched_barrier(0);
            __builtin_amdgcn_s_barrier();        // vmcnt naturally ~0 here; no exposure
        }
    }

    // stats: reduce across the 16 col-chunk threads of each row
#pragma unroll
    for (int i = 0; i < 4; ++i) {
#pragma unroll
        for (int off = 1; off < 16; off <<= 1) {
            sl[i] += __shfl_xor(sl[i], off);
            sql[i] += __shfl_xor(sql[i], off);
        }
    }
    if ((t & 15) == 0) {
#pragma unroll
        for (int i = 0; i < 4; ++i) {
            int r = rowbase + 64 * i;
            sP[(size_t)z * CH + r] = sl[i];
            sqP[(size_t)z * CH + r] = sql[i];
        }
    }

    float* Cp = cosP + (size_t)z * CH * CH;
#pragma unroll
    for (int mi = 0; mi < 4; ++mi)
#pragma unroll
        for (int nj = 0; nj < 4; ++nj) {
#pragma unroll
            for (int reg = 0; reg < 4; ++reg) {
                int r = wr + mi * 16 + fg * 4 + reg;
                int c = wc + nj * 16 + fr;
                Cp[(size_t)r * CH + c] = acc[mi][nj][reg];
            }
        }
#undef LOAD4
#undef CONVERT4
#undef MFMA_PHASE
}

// ---- K2: finalize per-(b,c) stats from the 8 q-partials ----
__global__ __launch_bounds__(256) void finalize_kernel(const float* __restrict__ sP,
                                                       const float* __restrict__ sqP,
                                                       float* __restrict__ s,
                                                       float* __restrict__ sq,
                                                       float* __restrict__ invn) {
    int b = blockIdx.x, c = threadIdx.x;
    float S = 0.f, Q = 0.f;
#pragma unroll
    for (int q = 0; q < 8; ++q) {
        S += sP[(size_t)(b * 8 + q) * CH + c];
        Q += sqP[(size_t)(b * 8 + q) * CH + c];
    }
    s[b * CH + c] = S;
    sq[b * CH + c] = Q;
    invn[b * CH + c] = 1.0f / fmaxf(sqrtf(Q), 1e-12f);
}

// ---- K3: weighted sum of partials -> R[256][256] (invn applied per batch) ----
__global__ __launch_bounds__(1024) void reduceP(const float* __restrict__ cosP,
                                                const float* __restrict__ invn,
                                                float* __restrict__ R) {
    int r = blockIdx.x;
    int t = threadIdx.x;
    int d = t & 255, pg = t >> 8;          // 4 groups of 8 batches
    const float* base = cosP + (size_t)r * CH + d;
    float acc = 0.f;
    for (int b = pg * 8; b < pg * 8 + 8; ++b) {
        float part = 0.f;
#pragma unroll
        for (int q = 0; q < 8; ++q)
            part += base[(size_t)(b * 8 + q) * (CH * CH)];
        acc += part * invn[b * CH + d] * invn[b * CH + r];
    }
    __shared__ float red[1024];
    red[t] = acc;
    __syncthreads();
    if (t < 256)
        R[(size_t)r * CH + t] = red[t] + red[t + 256] + red[t + 512] + red[t + 768];
}

// -------- K4: symmetrize (R + R^T) + top-8 smallest |cos| per column --------
__global__ __launch_bounds__(256) void symtopk(const float* __restrict__ R,
                                               int* __restrict__ idx) {
    int c = blockIdx.x;
    int d = threadIdx.x;
    float v = fabsf((R[(size_t)c * CH + d] + R[(size_t)d * CH + c]) * (0.5f / BATCH));

    __shared__ unsigned long long keys[CH];
    __shared__ unsigned long long wmin[4];
    __shared__ unsigned long long bmin;

    keys[d] = ((unsigned long long)__float_as_uint(v) << 32) | (unsigned)d;
    __syncthreads();

    for (int i = 0; i < KSEL; ++i) {
        unsigned long long k = keys[d];
        for (int off = 32; off; off >>= 1) {
            unsigned long long o = __shfl_down(k, off);
            k = (o < k) ? o : k;
        }
        if ((d & 63) == 0) wmin[d >> 6] = k;
        __syncthreads();
        if (d == 0) {
            unsigned long long m = wmin[0];
            if (wmin[1] < m) m = wmin[1];
            if (wmin[2] < m) m = wmin[2];
            if (wmin[3] < m) m = wmin[3];
            bmin = m;
            idx[c * KSEL + i] = (int)(m & 0xffffffffu);
        }
        __syncthreads();
        int sel = (int)(bmin & 0xffffffffu);
        if (d == sel) keys[d] = 0xffffffffffffffffULL;
        __syncthreads();
    }
}

// ---------------- K5: gathered group statistics ----------------
__global__ __launch_bounds__(256) void groupstat_kernel(const float* __restrict__ s,
                                                        const float* __restrict__ sq,
                                                        const int* __restrict__ idx,
                                                        float* __restrict__ mean,
                                                        float* __restrict__ inv) {
    int b = blockIdx.x, c = threadIdx.x;
    float gs = s[b * CH + c], gq = sq[b * CH + c];
#pragma unroll
    for (int i = 1; i < KSEL; ++i) {
        int d = idx[c * KSEL + i];
        gs += s[b * CH + d];
        gq += sq[b * CH + d];
    }
    const float Ninv = 1.0f / (float)(KSEL * HW);
    float m = gs * Ninv;
    float var = gq * Ninv - m * m;
    mean[b * CH + c] = m;
    inv[b * CH + c]  = rsqrtf(var + EPSV);
}

// ---------------- K6: normalize ----------------
__global__ __launch_bounds__(256) void norm_kernel(const float* __restrict__ x,
                                                   const float* __restrict__ mean,
                                                   const float* __restrict__ inv,
                                                   const float* __restrict__ gamma,
                                                   const float* __restrict__ beta,
                                                   float* __restrict__ out) {
    int i = blockIdx.x * 256 + threadIdx.x;
    int bc = i >> 10;
    int c  = bc & (CH - 1);
    float m = mean[bc], v = inv[bc];
    float g  = gamma[c] * v;
    float bt = beta[c] - m * g;
    float4 xv = ((const float4*)x)[i];
    float4 o;
    o.x = xv.x * g + bt;
    o.y = xv.y * g + bt;
    o.z = xv.z * g + bt;
    o.w = xv.w * g + bt;
    ((float4*)out)[i] = o;
}

extern "C" void kernel_launch(void* const* d_in, const int* in_sizes, int n_in,
                              void* d_out, int out_size, void* d_ws, size_t ws_size,
                              hipStream_t stream) {
    const float* x     = (const float*)d_in[0];
    const float* gamma = (const float*)d_in[1];
    const float* beta  = (const float*)d_in[2];
    float* out = (float*)d_out;

    // Gram partials (256 x 256KB = 64 MB) live in d_out; norm overwrites at end.
    float* cosP = (float*)d_out;

    float* ws   = (float*)d_ws;
    float* sP   = ws;                         // 256*256 partial s
    float* sqP  = sP + 256 * CH;              // 256*256 partial sq
    float* s    = sqP + 256 * CH;
    float* sq   = s + BATCH * CH;
    float* invn = sq + BATCH * CH;
    float* mean = invn + BATCH * CH;
    float* inv  = mean + BATCH * CH;
    float* R    = inv + BATCH * CH;           // 256*256
    int*   idx  = (int*)(R + CH * CH);        // 256*8

    gram256<<<256, 1024, 0, stream>>>(x, cosP, sP, sqP);
    finalize_kernel<<<BATCH, 256, 0, stream>>>(sP, sqP, s, sq, invn);
    reduceP<<<CH, 1024, 0, stream>>>(cosP, invn, R);
    symtopk<<<CH, 256, 0, stream>>>(R, idx);
    groupstat_kernel<<<BATCH, 256, 0, stream>>>(s, sq, idx, mean, inv);
    norm_kernel<<<(BATCH * CH * HW / 4) / 256, 256, 0, stream>>>(x, mean, inv, gamma, beta, out);
}

// Round 20
// 109.673 us; speedup vs baseline: 1.0157x; 1.0157x over previous
//
#include <hip/hip_runtime.h>
#include <math.h>

#define BATCH 32
#define CH 256
#define HW 4096
#define KSEL 8
#define EPSV 1e-5f

typedef __attribute__((ext_vector_type(8))) short short8;
typedef __attribute__((ext_vector_type(4))) float f32x4;

__device__ __forceinline__ void gload16(const void* g, void* l) {
    __builtin_amdgcn_global_load_lds((const __attribute__((address_space(1))) void*)g,
                                     (__attribute__((address_space(3))) void*)l, 16, 0, 0);
}

// ---- K1: raw-x Gram partials (256x256 per (b,q)) + fused s/sq partials ----
// Guide 2-phase shape (T3 minimum), DMA staging, wait AFTER compute:
//   ISSUE(k+1->ldsF[^1]) ; CONVERT(ldsF[k]->Hh/Hl) ; lgkm ; bar ;
//   MFMA ; vmcnt(0) [~free] ; bar
// global_load_lds = zero staging registers -> the R18/R19 regalloc collapse
// (f[] live across MFMA -> forced VGPR=64 + spill) is structurally impossible.
// KC=32, 16 chunks; ldsF dbuf 2x32KB; Hh/Hl single-buffer, 40-short row pitch
// (uniform bank spread); LDS 104KB; 1024 thr = 16 waves (4x4), wave tile
// 64x64, acc[4][4]=64 VGPR. C1 = H*(H+2L)^T trunc split (~1e-7 rel).
__global__ __launch_bounds__(1024) void gram256(const float* __restrict__ x,
                                                float* __restrict__ cosP,
                                                float* __restrict__ sP,
                                                float* __restrict__ sqP) {
    int z = blockIdx.x;             // 0..255
    int b = z >> 3, q = z & 7;      // klen = 512
    const float* xb = x + (size_t)b * CH * HW;
    int kbase = q * 512;

    __shared__ float4 ldsF[2][2048];            // 2 x 32 KB raw fp32 staging
    __shared__ unsigned short Hh[CH * 40];      // 20 KB (pitch 40 shorts = 80B)
    __shared__ unsigned short Hl[CH * 40];      // 20 KB

    int t = threadIdx.x, lane = t & 63, w = t >> 6;   // w 0..15
    int wr = (w >> 2) * 64, wc = (w & 3) * 64;
    int fr = lane & 15, fg = lane >> 4;

    int rl = lane >> 3;              // 0..7 row within slot
    int gs = lane & 7;               // granule (16B = 4 floats)

    float sl[2] = {}, sql[2] = {};
    f32x4 acc[4][4] = {};

#define ISSUE(KB, BUF) { int k0 = kbase + (KB) * 32;                               \
    _Pragma("unroll") for (int j = 0; j < 2; ++j) {                                \
        int row = (w * 2 + j) * 8 + rl;                                            \
        gload16(xb + (size_t)row * HW + k0 + gs * 4, &ldsF[BUF][(w * 2 + j) * 64]); \
    } }

#define CONVERT(BUF) { _Pragma("unroll") for (int j = 0; j < 2; ++j) {             \
    float4 v = ldsF[BUF][(w * 2 + j) * 64 + lane];                                 \
    int r = (w * 2 + j) * 8 + rl;                                                  \
    sl[j] += v.x + v.y + v.z + v.w;                                                \
    sql[j] += v.x * v.x + v.y * v.y + v.z * v.z + v.w * v.w;                       \
    unsigned u0 = __float_as_uint(v.x), u1 = __float_as_uint(v.y);                 \
    unsigned u2 = __float_as_uint(v.z), u3 = __float_as_uint(v.w);                 \
    unsigned hp0 = (u0 >> 16) | (u1 & 0xffff0000u);                                \
    unsigned hp1 = (u2 >> 16) | (u3 & 0xffff0000u);                                \
    float lo0 = v.x - __uint_as_float(u0 & 0xffff0000u);                           \
    float lo1 = v.y - __uint_as_float(u1 & 0xffff0000u);                           \
    float lo2 = v.z - __uint_as_float(u2 & 0xffff0000u);                           \
    float lo3 = v.w - __uint_as_float(u3 & 0xffff0000u);                           \
    lo0 += lo0; lo1 += lo1; lo2 += lo2; lo3 += lo3;                                \
    unsigned lp0 = (__float_as_uint(lo0) >> 16) | (__float_as_uint(lo1) & 0xffff0000u); \
    unsigned lp1 = (__float_as_uint(lo2) >> 16) | (__float_as_uint(lo3) & 0xffff0000u); \
    int adr = r * 40 + gs * 4;                                                     \
    *(uint2*)&Hh[adr] = make_uint2(hp0, hp1);                                      \
    *(uint2*)&Hl[adr] = make_uint2(lp0, lp1);                                      \
} }

// KC=32 = one MFMA K-step: lane k-fragment = cols fg*8..fg*8+7.
#define MFMA_PHASE {                                                               \
    short8 af[4], bb[4];                                                           \
    _Pragma("unroll") for (int mi = 0; mi < 4; ++mi)                               \
        af[mi] = *(const short8*)&Hh[(wr + mi * 16 + fr) * 40 + fg * 8];           \
    _Pragma("unroll") for (int nj = 0; nj < 4; ++nj)                               \
        bb[nj] = *(const short8*)&Hh[(wc + nj * 16 + fr) * 40 + fg * 8];           \
    _Pragma("unroll") for (int nj = 0; nj < 4; ++nj)                               \
        _Pragma("unroll") for (int mi = 0; mi < 4; ++mi)                           \
            acc[mi][nj] = __builtin_amdgcn_mfma_f32_16x16x32_bf16(af[mi], bb[nj], acc[mi][nj], 0, 0, 0); \
    _Pragma("unroll") for (int nj = 0; nj < 4; ++nj)                               \
        bb[nj] = *(const short8*)&Hl[(wc + nj * 16 + fr) * 40 + fg * 8];           \
    _Pragma("unroll") for (int nj = 0; nj < 4; ++nj)                               \
        _Pragma("unroll") for (int mi = 0; mi < 4; ++mi)                           \
            acc[mi][nj] = __builtin_amdgcn_mfma_f32_16x16x32_bf16(af[mi], bb[nj], acc[mi][nj], 0, 0, 0); \
}

    // prologue: DMA chunk 0
    ISSUE(0, 0)
    asm volatile("s_waitcnt vmcnt(0)" ::: "memory");
    __builtin_amdgcn_sched_barrier(0);
    __builtin_amdgcn_s_barrier();

#pragma unroll 1
    for (int kb = 0; kb < 16; ++kb) {
        if (kb < 15) ISSUE(kb + 1, (kb + 1) & 1)            // DMA next (0 regs)
        CONVERT(kb & 1)                                      // staged chunk kb -> Hh/Hl
        asm volatile("s_waitcnt lgkmcnt(0)" ::: "memory");   // own ds writes done
        __builtin_amdgcn_sched_barrier(0);
        __builtin_amdgcn_s_barrier();                        // H ready (vmcnt NOT drained)
        __builtin_amdgcn_sched_barrier(0);
        MFMA_PHASE                                           // DMA(kb+1) lands under this
        asm volatile("s_waitcnt vmcnt(0)" ::: "memory");     // ~free by now
        __builtin_amdgcn_sched_barrier(0);
        __builtin_amdgcn_s_barrier();                        // H consumed; ldsF[^1] complete
    }

    // stats: reduce over the 8 granule lanes of each row
#pragma unroll
    for (int j = 0; j < 2; ++j) {
#pragma unroll
        for (int off = 1; off < 8; off <<= 1) {
            sl[j] += __shfl_xor(sl[j], off);
            sql[j] += __shfl_xor(sql[j], off);
        }
    }
    if (gs == 0) {
#pragma unroll
        for (int j = 0; j < 2; ++j) {
            int r = (w * 2 + j) * 8 + rl;
            sP[(size_t)z * CH + r] = sl[j];
            sqP[(size_t)z * CH + r] = sql[j];
        }
    }

    float* Cp = cosP + (size_t)z * CH * CH;
#pragma unroll
    for (int mi = 0; mi < 4; ++mi)
#pragma unroll
        for (int nj = 0; nj < 4; ++nj) {
#pragma unroll
            for (int reg = 0; reg < 4; ++reg) {
                int r = wr + mi * 16 + fg * 4 + reg;
                int c = wc + nj * 16 + fr;
                Cp[(size_t)r * CH + c] = acc[mi][nj][reg];
            }
        }
#undef ISSUE
#undef CONVERT
#undef MFMA_PHASE
}

// ---- K2: finalize per-(b,c) stats from the 8 q-partials ----
__global__ __launch_bounds__(256) void finalize_kernel(const float* __restrict__ sP,
                                                       const float* __restrict__ sqP,
                                                       float* __restrict__ s,
                                                       float* __restrict__ sq,
                                                       float* __restrict__ invn) {
    int b = blockIdx.x, c = threadIdx.x;
    float S = 0.f, Q = 0.f;
#pragma unroll
    for (int q = 0; q < 8; ++q) {
        S += sP[(size_t)(b * 8 + q) * CH + c];
        Q += sqP[(size_t)(b * 8 + q) * CH + c];
    }
    s[b * CH + c] = S;
    sq[b * CH + c] = Q;
    invn[b * CH + c] = 1.0f / fmaxf(sqrtf(Q), 1e-12f);
}

// ---- K3: weighted sum of partials -> R[256][256] (invn applied per batch) ----
__global__ __launch_bounds__(1024) void reduceP(const float* __restrict__ cosP,
                                                const float* __restrict__ invn,
                                                float* __restrict__ R) {
    int r = blockIdx.x;
    int t = threadIdx.x;
    int d = t & 255, pg = t >> 8;          // 4 groups of 8 batches
    const float* base = cosP + (size_t)r * CH + d;
    float acc = 0.f;
    for (int b = pg * 8; b < pg * 8 + 8; ++b) {
        float part = 0.f;
#pragma unroll
        for (int q = 0; q < 8; ++q)
            part += base[(size_t)(b * 8 + q) * (CH * CH)];
        acc += part * invn[b * CH + d] * invn[b * CH + r];
    }
    __shared__ float red[1024];
    red[t] = acc;
    __syncthreads();
    if (t < 256)
        R[(size_t)r * CH + t] = red[t] + red[t + 256] + red[t + 512] + red[t + 768];
}

// -------- K4: symmetrize (R + R^T) + top-8 smallest |cos| per column --------
__global__ __launch_bounds__(256) void symtopk(const float* __restrict__ R,
                                               int* __restrict__ idx) {
    int c = blockIdx.x;
    int d = threadIdx.x;
    float v = fabsf((R[(size_t)c * CH + d] + R[(size_t)d * CH + c]) * (0.5f / BATCH));

    __shared__ unsigned long long keys[CH];
    __shared__ unsigned long long wmin[4];
    __shared__ unsigned long long bmin;

    keys[d] = ((unsigned long long)__float_as_uint(v) << 32) | (unsigned)d;
    __syncthreads();

    for (int i = 0; i < KSEL; ++i) {
        unsigned long long k = keys[d];
        for (int off = 32; off; off >>= 1) {
            unsigned long long o = __shfl_down(k, off);
            k = (o < k) ? o : k;
        }
        if ((d & 63) == 0) wmin[d >> 6] = k;
        __syncthreads();
        if (d == 0) {
            unsigned long long m = wmin[0];
            if (wmin[1] < m) m = wmin[1];
            if (wmin[2] < m) m = wmin[2];
            if (wmin[3] < m) m = wmin[3];
            bmin = m;
            idx[c * KSEL + i] = (int)(m & 0xffffffffu);
        }
        __syncthreads();
        int sel = (int)(bmin & 0xffffffffu);
        if (d == sel) keys[d] = 0xffffffffffffffffULL;
        __syncthreads();
    }
}

// ---------------- K5: gathered group statistics ----------------
__global__ __launch_bounds__(256) void groupstat_kernel(const float* __restrict__ s,
                                                        const float* __restrict__ sq,
                                                        const int* __restrict__ idx,
                                                        float* __restrict__ mean,
                                                        float* __restrict__ inv) {
    int b = blockIdx.x, c = threadIdx.x;
    float gs = s[b * CH + c], gq = sq[b * CH + c];
#pragma unroll
    for (int i = 1; i < KSEL; ++i) {
        int d = idx[c * KSEL + i];
        gs += s[b * CH + d];
        gq += sq[b * CH + d];
    }
    const float Ninv = 1.0f / (float)(KSEL * HW);
    float m = gs * Ninv;
    float var = gq * Ninv - m * m;
    mean[b * CH + c] = m;
    inv[b * CH + c]  = rsqrtf(var + EPSV);
}

// ---------------- K6: normalize ----------------
__global__ __launch_bounds__(256) void norm_kernel(const float* __restrict__ x,
                                                   const float* __restrict__ mean,
                                                   const float* __restrict__ inv,
                                                   const float* __restrict__ gamma,
                                                   const float* __restrict__ beta,
                                                   float* __restrict__ out) {
    int i = blockIdx.x * 256 + threadIdx.x;
    int bc = i >> 10;
    int c  = bc & (CH - 1);
    float m = mean[bc], v = inv[bc];
    float g  = gamma[c] * v;
    float bt = beta[c] - m * g;
    float4 xv = ((const float4*)x)[i];
    float4 o;
    o.x = xv.x * g + bt;
    o.y = xv.y * g + bt;
    o.z = xv.z * g + bt;
    o.w = xv.w * g + bt;
    ((float4*)out)[i] = o;
}

extern "C" void kernel_launch(void* const* d_in, const int* in_sizes, int n_in,
                              void* d_out, int out_size, void* d_ws, size_t ws_size,
                              hipStream_t stream) {
    const float* x     = (const float*)d_in[0];
    const float* gamma = (const float*)d_in[1];
    const float* beta  = (const float*)d_in[2];
    float* out = (float*)d_out;

    // Gram partials (256 x 256KB = 64 MB) live in d_out; norm overwrites at end.
    float* cosP = (float*)d_out;

    float* ws   = (float*)d_ws;
    float* sP   = ws;                         // 256*256 partial s
    float* sqP  = sP + 256 * CH;              // 256*256 partial sq
    float* s    = sqP + 256 * CH;
    float* sq   = s + BATCH * CH;
    float* invn = sq + BATCH * CH;
    float* mean = invn + BATCH * CH;
    float* inv  = mean + BATCH * CH;
    float* R    = inv + BATCH * CH;           // 256*256
    int*   idx  = (int*)(R + CH * CH);        // 256*8

    gram256<<<256, 1024, 0, stream>>>(x, cosP, sP, sqP);
    finalize_kernel<<<BATCH, 256, 0, stream>>>(sP, sqP, s, sq, invn);
    reduceP<<<CH, 1024, 0, stream>>>(cosP, invn, R);
    symtopk<<<CH, 256, 0, stream>>>(R, idx);
    groupstat_kernel<<<BATCH, 256, 0, stream>>>(s, sq, idx, mean, inv);
    norm_kernel<<<(BATCH * CH * HW / 4) / 256, 256, 0, stream>>>(x, mean, inv, gamma, beta, out);
}

// Round 21
// 102.100 us; speedup vs baseline: 1.0910x; 1.0742x over previous
//
#include <hip/hip_runtime.h>
#include <math.h>

#define BATCH 32
#define CH 256
#define HW 4096
#define KSEL 8
#define EPSV 1e-5f

typedef __attribute__((ext_vector_type(8))) short short8;
typedef __attribute__((ext_vector_type(4))) float f32x4;

// ---- K1: raw-x Gram partials (UPPER-TRIANGLE tiles per (b,q)) + s/sq ----
// Base = best-measured kernel (103.2us total): 1024 thr = 16 waves (4x4),
// wave tile 64x64, acc[4][4]=64 VGPR, LDS dbuf 128KB, ONE raw s_barrier per
// chunk, no scheduling pins beyond the required lgkmcnt(0).
// NEW: C = C^T symmetry -- the 6 strictly-lower waves (wr > wc) skip MFMA and
// C-write (they still stage/convert and hit barriers). MFMA work -37.5%,
// C-write 64->40 MB. reduceP/symtopk read only the upper triangle.
// Data path = R7 proven: coalesced wave loads -> reg trunc-split convert ->
// LDS stride 128B + 3-bit granule XOR (0 conflicts) -> bf16 16x16x32 MFMA.
// C1 = H*(H+2L)^T trunc split (drops L*L^T, ~1e-7 rel).
__global__ __launch_bounds__(1024) void gram256(const float* __restrict__ x,
                                                float* __restrict__ cosP,
                                                float* __restrict__ sP,
                                                float* __restrict__ sqP) {
    int z = blockIdx.x;             // 0..255
    int b = z >> 3, q = z & 7;      // klen = 512
    const float* xb = x + (size_t)b * CH * HW;

    __shared__ unsigned short Hh[2][CH * 64];   // 2 x 32 KB
    __shared__ unsigned short Hl[2][CH * 64];   // 2 x 32 KB

    int t = threadIdx.x, lane = t & 63, w = t >> 6;   // w 0..15
    int wr = (w >> 2) * 64, wc = (w & 3) * 64;
    int fr = lane & 15, fg = lane >> 4;
    const bool upperw = (wr <= wc);   // lower waves duplicate transpose work

    // staging geometry (coalesced: 4 x 1KB contiguous per wave-load instr)
    int rowbase = t >> 4;            // 0..63 ; row_i = rowbase + 64*i
    int col16 = t & 15;              // 16B chunk within the 256B row-chunk
    int gr = col16 >> 1;             // granule 0..7
    int halfo = (col16 & 1) * 4;     // short offset within granule
    const float4* srcb4 = (const float4*)xb + (size_t)rowbase * (HW / 4) + q * 128 + col16;

    float sl[4] = {}, sql[4] = {};
    f32x4 acc[4][4] = {};
    float4 f[4];

#define LOAD4(KB) { const float4* sp = srcb4 + (size_t)(KB) * 16;                  \
    _Pragma("unroll") for (int i = 0; i < 4; ++i) f[i] = sp[(size_t)i * 65536]; }

#define CONVERT4(BUF) { _Pragma("unroll") for (int i = 0; i < 4; ++i) {            \
    float4 v = f[i];                                                               \
    sl[i] += v.x + v.y + v.z + v.w;                                                \
    sql[i] += v.x * v.x + v.y * v.y + v.z * v.z + v.w * v.w;                       \
    unsigned u0 = __float_as_uint(v.x), u1 = __float_as_uint(v.y);                 \
    unsigned u2 = __float_as_uint(v.z), u3 = __float_as_uint(v.w);                 \
    unsigned hp0 = (u0 >> 16) | (u1 & 0xffff0000u);                                \
    unsigned hp1 = (u2 >> 16) | (u3 & 0xffff0000u);                                \
    float lo0 = v.x - __uint_as_float(u0 & 0xffff0000u);                           \
    float lo1 = v.y - __uint_as_float(u1 & 0xffff0000u);                           \
    float lo2 = v.z - __uint_as_float(u2 & 0xffff0000u);                           \
    float lo3 = v.w - __uint_as_float(u3 & 0xffff0000u);                           \
    lo0 += lo0; lo1 += lo1; lo2 += lo2; lo3 += lo3;                                \
    unsigned lp0 = (__float_as_uint(lo0) >> 16) | (__float_as_uint(lo1) & 0xffff0000u); \
    unsigned lp1 = (__float_as_uint(lo2) >> 16) | (__float_as_uint(lo3) & 0xffff0000u); \
    int r = rowbase + 64 * i;                                                      \
    int adr = r * 64 + ((gr ^ (r & 7)) * 8) + halfo;                               \
    *(uint2*)&Hh[BUF][adr] = make_uint2(hp0, hp1);                                 \
    *(uint2*)&Hl[BUF][adr] = make_uint2(lp0, lp1);                                 \
} }

// bh-pass then bl-pass: same-acc MFMAs separated by 16 independent instrs.
#define MFMA_PHASE(BUF) { _Pragma("unroll") for (int ks = 0; ks < 2; ++ks) {       \
    int gk = ks * 4 + fg;                                                          \
    short8 af[4], bb[4];                                                           \
    _Pragma("unroll") for (int mi = 0; mi < 4; ++mi) {                             \
        int r = wr + mi * 16 + fr;                                                 \
        af[mi] = *(const short8*)&Hh[BUF][r * 64 + ((gk ^ (r & 7)) * 8)];          \
    }                                                                              \
    _Pragma("unroll") for (int nj = 0; nj < 4; ++nj) {                             \
        int r = wc + nj * 16 + fr;                                                 \
        bb[nj] = *(const short8*)&Hh[BUF][r * 64 + ((gk ^ (r & 7)) * 8)];          \
    }                                                                              \
    _Pragma("unroll") for (int nj = 0; nj < 4; ++nj)                               \
        _Pragma("unroll") for (int mi = 0; mi < 4; ++mi)                           \
            acc[mi][nj] = __builtin_amdgcn_mfma_f32_16x16x32_bf16(af[mi], bb[nj], acc[mi][nj], 0, 0, 0); \
    _Pragma("unroll") for (int nj = 0; nj < 4; ++nj) {                             \
        int r = wc + nj * 16 + fr;                                                 \
        bb[nj] = *(const short8*)&Hl[BUF][r * 64 + ((gk ^ (r & 7)) * 8)];          \
    }                                                                              \
    _Pragma("unroll") for (int nj = 0; nj < 4; ++nj)                               \
        _Pragma("unroll") for (int mi = 0; mi < 4; ++mi)                           \
            acc[mi][nj] = __builtin_amdgcn_mfma_f32_16x16x32_bf16(af[mi], bb[nj], acc[mi][nj], 0, 0, 0); \
} }

    // prologue: issue chunk 0 loads
    LOAD4(0)

#pragma unroll 1
    for (int kb = 0; kb < 8; ++kb) {
        CONVERT4(kb & 1)                                    // compiler inserts counted vmcnt per f-use
        if (kb < 7) LOAD4(kb + 1)                           // prefetch; compiler places optimally
        asm volatile("s_waitcnt lgkmcnt(0)" ::: "memory");  // own ds_writes done before barrier
        __builtin_amdgcn_sched_barrier(0);
        __builtin_amdgcn_s_barrier();                       // buf[kb&1] ready (vmcnt NOT drained)
        if (upperw) { MFMA_PHASE(kb & 1) }                  // lower waves skip (transpose dup)
        // no trailing barrier: next convert targets the other buffer
    }

    // stats: reduce across the 16 col-chunk threads of each row
#pragma unroll
    for (int i = 0; i < 4; ++i) {
#pragma unroll
        for (int off = 1; off < 16; off <<= 1) {
            sl[i] += __shfl_xor(sl[i], off);
            sql[i] += __shfl_xor(sql[i], off);
        }
    }
    if ((t & 15) == 0) {
#pragma unroll
        for (int i = 0; i < 4; ++i) {
            int r = rowbase + 64 * i;
            sP[(size_t)z * CH + r] = sl[i];
            sqP[(size_t)z * CH + r] = sql[i];
        }
    }

    if (upperw) {
        float* Cp = cosP + (size_t)z * CH * CH;
#pragma unroll
        for (int mi = 0; mi < 4; ++mi)
#pragma unroll
            for (int nj = 0; nj < 4; ++nj) {
#pragma unroll
                for (int reg = 0; reg < 4; ++reg) {
                    int r = wr + mi * 16 + fg * 4 + reg;
                    int c = wc + nj * 16 + fr;
                    Cp[(size_t)r * CH + c] = acc[mi][nj][reg];
                }
            }
    }
#undef LOAD4
#undef CONVERT4
#undef MFMA_PHASE
}

// ---- K2: finalize per-(b,c) stats from the 8 q-partials ----
__global__ __launch_bounds__(256) void finalize_kernel(const float* __restrict__ sP,
                                                       const float* __restrict__ sqP,
                                                       float* __restrict__ s,
                                                       float* __restrict__ sq,
                                                       float* __restrict__ invn) {
    int b = blockIdx.x, c = threadIdx.x;
    float S = 0.f, Q = 0.f;
#pragma unroll
    for (int q = 0; q < 8; ++q) {
        S += sP[(size_t)(b * 8 + q) * CH + c];
        Q += sqP[(size_t)(b * 8 + q) * CH + c];
    }
    s[b * CH + c] = S;
    sq[b * CH + c] = Q;
    invn[b * CH + c] = 1.0f / fmaxf(sqrtf(Q), 1e-12f);
}

// ---- K3: weighted sum of partials -> upper-tri R (invn applied per batch) ----
__global__ __launch_bounds__(1024) void reduceP(const float* __restrict__ cosP,
                                                const float* __restrict__ invn,
                                                float* __restrict__ R) {
    int r = blockIdx.x;
    int t = threadIdx.x;
    int d = t & 255, pg = t >> 8;          // 4 groups of 8 batches
    const float* base = cosP + (size_t)r * CH + d;
    float acc = 0.f;
    if (d >= r) {                          // only the written (upper) triangle
        for (int b = pg * 8; b < pg * 8 + 8; ++b) {
            float part = 0.f;
#pragma unroll
            for (int q = 0; q < 8; ++q)
                part += base[(size_t)(b * 8 + q) * (CH * CH)];
            acc += part * invn[b * CH + d] * invn[b * CH + r];
        }
    }
    __shared__ float red[1024];
    red[t] = acc;
    __syncthreads();
    if (t < 256)
        R[(size_t)r * CH + t] = red[t] + red[t + 256] + red[t + 512] + red[t + 768];
}

// -------- K4: top-8 smallest |cos| per column (upper-tri R lookup) --------
__global__ __launch_bounds__(256) void symtopk(const float* __restrict__ R,
                                               int* __restrict__ idx) {
    int c = blockIdx.x;
    int d = threadIdx.x;
    int rr = (c < d) ? c : d, cc = (c < d) ? d : c;
    float v = fabsf(R[(size_t)rr * CH + cc] * (1.0f / BATCH));

    __shared__ unsigned long long keys[CH];
    __shared__ unsigned long long wmin[4];
    __shared__ unsigned long long bmin;

    keys[d] = ((unsigned long long)__float_as_uint(v) << 32) | (unsigned)d;
    __syncthreads();

    for (int i = 0; i < KSEL; ++i) {
        unsigned long long k = keys[d];
        for (int off = 32; off; off >>= 1) {
            unsigned long long o = __shfl_down(k, off);
            k = (o < k) ? o : k;
        }
        if ((d & 63) == 0) wmin[d >> 6] = k;
        __syncthreads();
        if (d == 0) {
            unsigned long long m = wmin[0];
            if (wmin[1] < m) m = wmin[1];
            if (wmin[2] < m) m = wmin[2];
            if (wmin[3] < m) m = wmin[3];
            bmin = m;
            idx[c * KSEL + i] = (int)(m & 0xffffffffu);
        }
        __syncthreads();
        int sel = (int)(bmin & 0xffffffffu);
        if (d == sel) keys[d] = 0xffffffffffffffffULL;
        __syncthreads();
    }
}

// ---------------- K5: gathered group statistics ----------------
__global__ __launch_bounds__(256) void groupstat_kernel(const float* __restrict__ s,
                                                        const float* __restrict__ sq,
                                                        const int* __restrict__ idx,
                                                        float* __restrict__ mean,
                                                        float* __restrict__ inv) {
    int b = blockIdx.x, c = threadIdx.x;
    float gs = s[b * CH + c], gq = sq[b * CH + c];
#pragma unroll
    for (int i = 1; i < KSEL; ++i) {
        int d = idx[c * KSEL + i];
        gs += s[b * CH + d];
        gq += sq[b * CH + d];
    }
    const float Ninv = 1.0f / (float)(KSEL * HW);
    float m = gs * Ninv;
    float var = gq * Ninv - m * m;
    mean[b * CH + c] = m;
    inv[b * CH + c]  = rsqrtf(var + EPSV);
}

// ---------------- K6: normalize ----------------
__global__ __launch_bounds__(256) void norm_kernel(const float* __restrict__ x,
                                                   const float* __restrict__ mean,
                                                   const float* __restrict__ inv,
                                                   const float* __restrict__ gamma,
                                                   const float* __restrict__ beta,
                                                   float* __restrict__ out) {
    int i = blockIdx.x * 256 + threadIdx.x;
    int bc = i >> 10;
    int c  = bc & (CH - 1);
    float m = mean[bc], v = inv[bc];
    float g  = gamma[c] * v;
    float bt = beta[c] - m * g;
    float4 xv = ((const float4*)x)[i];
    float4 o;
    o.x = xv.x * g + bt;
    o.y = xv.y * g + bt;
    o.z = xv.z * g + bt;
    o.w = xv.w * g + bt;
    ((float4*)out)[i] = o;
}

extern "C" void kernel_launch(void* const* d_in, const int* in_sizes, int n_in,
                              void* d_out, int out_size, void* d_ws, size_t ws_size,
                              hipStream_t stream) {
    const float* x     = (const float*)d_in[0];
    const float* gamma = (const float*)d_in[1];
    const float* beta  = (const float*)d_in[2];
    float* out = (float*)d_out;

    // Gram partials (upper tiles, 40 MB) live in d_out; reduceP reads only the
    // written triangle; norm overwrites all of d_out at the end (deterministic).
    float* cosP = (float*)d_out;

    float* ws   = (float*)d_ws;
    float* sP   = ws;                         // 256*256 partial s
    float* sqP  = sP + 256 * CH;              // 256*256 partial sq
    float* s    = sqP + 256 * CH;
    float* sq   = s + BATCH * CH;
    float* invn = sq + BATCH * CH;
    float* mean = invn + BATCH * CH;
    float* inv  = mean + BATCH * CH;
    float* R    = inv + BATCH * CH;           // 256*256 (upper tri valid)
    int*   idx  = (int*)(R + CH * CH);        // 256*8

    gram256<<<256, 1024, 0, stream>>>(x, cosP, sP, sqP);
    finalize_kernel<<<BATCH, 256, 0, stream>>>(sP, sqP, s, sq, invn);
    reduceP<<<CH, 1024, 0, stream>>>(cosP, invn, R);
    symtopk<<<CH, 256, 0, stream>>>(R, idx);
    groupstat_kernel<<<BATCH, 256, 0, stream>>>(s, sq, idx, mean, inv);
    norm_kernel<<<(BATCH * CH * HW / 4) / 256, 256, 0, stream>>>(x, mean, inv, gamma, beta, out);
}